// Round 8
// baseline (345.580 us; speedup 1.0000x reference)
//
#include <hip/hip_runtime.h>
#include <hip/hip_bf16.h>

#define RR 100
#define MID 256
#define NN 384
#define KP 128   // rank padded to 128 (zeros in r=100..127)

typedef __attribute__((ext_vector_type(8))) __bf16 bf16x8;
typedef __attribute__((ext_vector_type(4))) float floatx4;
typedef unsigned short ushort_t;

// Swizzled LDS offset (elements) for row-major [rows][KP] bf16 tiles stored as
// 16 chunks of 8 bf16 per row; chunk index XOR'd with (row&15) so that
// MFMA fragment reads (16 rows x same chunk) spread across all 32 banks.
#define SW(row, ch) ((((row) << 7)) + ((((ch) ^ ((row) & 15))) << 3))

__device__ __forceinline__ ushort_t f2bf(float f) {
  __hip_bfloat16 h = __float2bfloat16(f);
  return __builtin_bit_cast(ushort_t, h);
}

// ---------------- Factor nets (all three in one launch) ----------------
__global__ __launch_bounds__(256) void factors_kernel(
    const float* __restrict__ xA, const float* __restrict__ xB,
    const float* __restrict__ xC,
    const float* __restrict__ AW1, const float* __restrict__ Ab1,
    const float* __restrict__ AW2, const float* __restrict__ Ab2,
    const float* __restrict__ BW1, const float* __restrict__ Bb1,
    const float* __restrict__ BW2, const float* __restrict__ Bb2,
    const float* __restrict__ CW1, const float* __restrict__ Cb1,
    const float* __restrict__ CW2, const float* __restrict__ Cb2,
    const float* __restrict__ CW3, const float* __restrict__ Cb3,
    float* __restrict__ Af, float* __restrict__ Bf,
    ushort_t* __restrict__ Cbf) {
  __shared__ float h[MID];
  __shared__ float h2[MID];
  const int i = blockIdx.x;
  const int net = blockIdx.y;
  const int t = threadIdx.x;

  const float* x  = (net == 0) ? xA  : (net == 1) ? xB  : xC;
  const float* W1 = (net == 0) ? AW1 : (net == 1) ? BW1 : CW1;
  const float* b1 = (net == 0) ? Ab1 : (net == 1) ? Bb1 : Cb1;

  const float xv = x[i];
  h[t] = sinf(1.5f * (xv * W1[t] + b1[t]));
  __syncthreads();

  const float* hlast = h;
  if (net == 2) {  // block-uniform branch
    float acc = Cb2[t];
    const float* __restrict__ w = &CW2[t * MID];
#pragma unroll 4
    for (int m = 0; m < MID; m += 4) {
      const float4 wv = *(const float4*)&w[m];
      const float4 hv = *(const float4*)&h[m];
      acc += hv.x * wv.x;
      acc += hv.y * wv.y;
      acc += hv.z * wv.z;
      acc += hv.w * wv.w;
    }
    h2[t] = sinf(1.5f * acc);
    __syncthreads();
    hlast = h2;
  }

  const float* W2 = (net == 0) ? AW2 : (net == 1) ? BW2 : CW3;
  const float* b2 = (net == 0) ? Ab2 : (net == 1) ? Bb2 : Cb3;

  if (t < KP) {
    float v = 0.0f;
    if (t < RR) {
      float acc = b2[t];
      const float* __restrict__ w = &W2[t * MID];
#pragma unroll 4
      for (int m = 0; m < MID; m += 4) {
        const float4 wv = *(const float4*)&w[m];
        const float4 hv = *(const float4*)&hlast[m];
        acc += hv.x * wv.x;
        acc += hv.y * wv.y;
        acc += hv.z * wv.z;
        acc += hv.w * wv.w;
      }
      v = acc;
    }
    if (net == 0)      Af[i * KP + t] = v;
    else if (net == 1) Bf[i * KP + t] = v;
    else               Cbf[i * KP + t] = f2bf(v);
  }
}

// ---------------- CP contraction via bf16 MFMA ----------------
// R7 contiguous-slab structure (block = (i, j0) -> out[i, j0:j0+64, 0:384],
// bijective XCD swizzle, 48 KB LDS, occ 3) with two pipelining grafts:
//  * T14 async-STAGE: C k-tile kt+1 is prefetched global->regs while kt
//    computes; after the barrier it is only ds_write'n (HBM latency hidden
//    under MFMA, staging read-stall off the critical path).
//  * kf-major MFMA with immediate stores: for kf {4 chained MFMA; store}
//    spreads the 8 output stores through the MFMA phase instead of a burst
//    at the end, keeping the HBM write pipe fed during compute.
// W fragments are hoisted to registers once (Wt immutable after fold).
__global__ __launch_bounds__(256, 3) void cp_mfma(
    const float* __restrict__ Af, const float* __restrict__ Bf,
    const ushort_t* __restrict__ Cbf, float* __restrict__ out) {
  __shared__ ushort_t Wt[64 * KP];    // 16 KB
  __shared__ ushort_t Ct[128 * KP];   // 32 KB

  // bijective XCD swizzle: 2304 blocks = 8 XCDs x 288
  const int bid = blockIdx.x;
  const int swz = (bid & 7) * 288 + (bid >> 3);
  const int i   = swz / 6;
  const int j0  = (swz % 6) * 64;
  const int t   = threadIdx.x;

  // ---- fold W band [64][128]: 4 threads per j-row, 32 r's each ----
  {
    const int jx = t >> 2;
    const int q  = t & 3;
    const float* __restrict__ arow = Af + (size_t)i * KP + q * 32;
    const float* __restrict__ brow = Bf + (size_t)(j0 + jx) * KP + q * 32;
#pragma unroll
    for (int c = 0; c < 4; ++c) {
      const float4 a0 = *(const float4*)(arow + c * 8);
      const float4 a1 = *(const float4*)(arow + c * 8 + 4);
      const float4 b0 = *(const float4*)(brow + c * 8);
      const float4 b1 = *(const float4*)(brow + c * 8 + 4);
      uint4 wv;
      wv.x = (unsigned)f2bf(a0.x * b0.x) | ((unsigned)f2bf(a0.y * b0.y) << 16);
      wv.y = (unsigned)f2bf(a0.z * b0.z) | ((unsigned)f2bf(a0.w * b0.w) << 16);
      wv.z = (unsigned)f2bf(a1.x * b1.x) | ((unsigned)f2bf(a1.y * b1.y) << 16);
      wv.w = (unsigned)f2bf(a1.z * b1.z) | ((unsigned)f2bf(a1.w * b1.w) << 16);
      *(uint4*)&Wt[SW(jx, q * 4 + c)] = wv;
    }
  }

  const int lane = t & 63;
  const int w    = t >> 6;       // wave owns j-band [j0 + w*16, +16)
  const int m16  = lane & 15;
  const int g    = lane >> 4;
  const int jrow = j0 + w * 16 + m16;
  const size_t obase = (size_t)i * NN * NN + (size_t)jrow * NN;

  // ---- staging geometry: thread t always handles rows (t>>4)+16*it, chunk t&15
  const int crow = t >> 4;
  const int cch  = t & 15;
  const ushort_t* __restrict__ csrc = Cbf + (size_t)crow * KP + cch * 8;
  const int swbase = SW(crow, cch);  // LDS dest for it=0 (row+16 adds 16<<7)

  uint4 ca[8], cb[8];
  // prefetch k-tile 0
#pragma unroll
  for (int it = 0; it < 8; ++it)
    ca[it] = *(const uint4*)(csrc + (size_t)(16 * it) * KP);

#define DS_WRITE(BUF)                                                        \
  {                                                                          \
    _Pragma("unroll") for (int it = 0; it < 8; ++it) {                       \
      *(uint4*)&Ct[SW(crow + 16 * it, cch)] = BUF[it];                       \
    }                                                                        \
  }

#define PREFETCH(BUF, KT)                                                    \
  {                                                                          \
    _Pragma("unroll") for (int it = 0; it < 8; ++it) {                       \
      BUF[it] = *(const uint4*)(csrc + (size_t)((KT) * 128 + 16 * it) * KP); \
    }                                                                        \
  }

#define COMPUTE_STORE(KT)                                                    \
  {                                                                          \
    const int kb = (KT) * 128 + g * 4;                                       \
    _Pragma("unroll") for (int kf = 0; kf < 8; ++kf) {                       \
      floatx4 a = (floatx4)0.0f;                                             \
      _Pragma("unroll") for (int ks = 0; ks < 4; ++ks) {                     \
        const bf16x8 cf =                                                    \
            *(const bf16x8*)&Ct[SW(kf * 16 + m16, ks * 4 + g)];              \
        a = __builtin_amdgcn_mfma_f32_16x16x32_bf16(cf, wfr[ks], a, 0, 0, 0);\
      }                                                                      \
      *(floatx4*)&out[obase + kb + kf * 16] = a;                             \
    }                                                                        \
  }

  // ---- kt = 0 ----
  DS_WRITE(ca);
  PREFETCH(cb, 1);          // in flight under kt=0 compute
  __syncthreads();          // Wt + Ct(kt0) visible

  bf16x8 wfr[4];            // W fragments: Wt immutable from here on
#pragma unroll
  for (int ks = 0; ks < 4; ++ks)
    wfr[ks] = *(const bf16x8*)&Wt[SW(w * 16 + m16, ks * 4 + g)];

  COMPUTE_STORE(0);

  // ---- kt = 1 ----
  __syncthreads();          // all waves done reading Ct(kt0)
  DS_WRITE(cb);             // vmcnt wait on cb inserted by compiler
  PREFETCH(ca, 2);          // in flight under kt=1 compute
  __syncthreads();          // Ct(kt1) visible
  COMPUTE_STORE(1);

  // ---- kt = 2 ----
  __syncthreads();
  DS_WRITE(ca);
  __syncthreads();
  COMPUTE_STORE(2);

#undef DS_WRITE
#undef PREFETCH
#undef COMPUTE_STORE
}

extern "C" void kernel_launch(void* const* d_in, const int* in_sizes, int n_in,
                              void* d_out, int out_size, void* d_ws, size_t ws_size,
                              hipStream_t stream) {
  const float* A_input = (const float*)d_in[0];
  const float* B_input = (const float*)d_in[1];
  const float* C_input = (const float*)d_in[2];
  const float* A_W1 = (const float*)d_in[3];
  const float* A_b1 = (const float*)d_in[4];
  const float* A_W2 = (const float*)d_in[5];
  const float* A_b2 = (const float*)d_in[6];
  const float* B_W1 = (const float*)d_in[7];
  const float* B_b1 = (const float*)d_in[8];
  const float* B_W2 = (const float*)d_in[9];
  const float* B_b2 = (const float*)d_in[10];
  const float* C_W1 = (const float*)d_in[11];
  const float* C_b1 = (const float*)d_in[12];
  const float* C_W2 = (const float*)d_in[13];
  const float* C_b2 = (const float*)d_in[14];
  const float* C_W3 = (const float*)d_in[15];
  const float* C_b3 = (const float*)d_in[16];

  // ws layout: Af fp32 [384][128] | Bf fp32 [384][128] | Cbf bf16 [384][128]
  float* Af = (float*)d_ws;                       // 196,608 B
  float* Bf = Af + NN * KP;                       // 196,608 B
  ushort_t* Cbf = (ushort_t*)(Bf + NN * KP);      //  98,304 B  (total 480 KB)

  dim3 fgrid(NN, 3);
  factors_kernel<<<fgrid, 256, 0, stream>>>(
      A_input, B_input, C_input,
      A_W1, A_b1, A_W2, A_b2,
      B_W1, B_b1, B_W2, B_b2,
      C_W1, C_b1, C_W2, C_b2, C_W3, C_b3,
      Af, Bf, Cbf);

  // 2304 blocks = (NN/64 j-slabs) x (NN i)
  cp_mfma<<<dim3((NN / 64) * NN), 256, 0, stream>>>(Af, Bf, Cbf, (float*)d_out);
}

// Round 9
// 290.942 us; speedup vs baseline: 1.1878x; 1.1878x over previous
//
#include <hip/hip_runtime.h>
#include <hip/hip_bf16.h>

#define RR 100
#define MID 256
#define NN 384
#define KP 128   // rank padded to 128 (zeros in r=100..127)

typedef __attribute__((ext_vector_type(8))) __bf16 bf16x8;
typedef __attribute__((ext_vector_type(4))) float floatx4;
typedef unsigned short ushort_t;

// Swizzled LDS offset (elements) for row-major [rows][KP] bf16 tiles stored as
// 16 chunks of 8 bf16 per row; chunk index XOR'd with (row&15) so that
// MFMA fragment reads (16 rows x same chunk) spread across all 32 banks.
#define SW(row, ch) ((((row) << 7)) + ((((ch) ^ ((row) & 15))) << 3))

__device__ __forceinline__ ushort_t f2bf(float f) {
  __hip_bfloat16 h = __float2bfloat16(f);
  return __builtin_bit_cast(ushort_t, h);
}

// ---------------- Factor nets (all three in one launch) ----------------
__global__ __launch_bounds__(256) void factors_kernel(
    const float* __restrict__ xA, const float* __restrict__ xB,
    const float* __restrict__ xC,
    const float* __restrict__ AW1, const float* __restrict__ Ab1,
    const float* __restrict__ AW2, const float* __restrict__ Ab2,
    const float* __restrict__ BW1, const float* __restrict__ Bb1,
    const float* __restrict__ BW2, const float* __restrict__ Bb2,
    const float* __restrict__ CW1, const float* __restrict__ Cb1,
    const float* __restrict__ CW2, const float* __restrict__ Cb2,
    const float* __restrict__ CW3, const float* __restrict__ Cb3,
    float* __restrict__ Af, float* __restrict__ Bf,
    ushort_t* __restrict__ Cbf) {
  __shared__ float h[MID];
  __shared__ float h2[MID];
  const int i = blockIdx.x;
  const int net = blockIdx.y;
  const int t = threadIdx.x;

  const float* x  = (net == 0) ? xA  : (net == 1) ? xB  : xC;
  const float* W1 = (net == 0) ? AW1 : (net == 1) ? BW1 : CW1;
  const float* b1 = (net == 0) ? Ab1 : (net == 1) ? Bb1 : Cb1;

  const float xv = x[i];
  h[t] = sinf(1.5f * (xv * W1[t] + b1[t]));
  __syncthreads();

  const float* hlast = h;
  if (net == 2) {  // block-uniform branch
    float acc = Cb2[t];
    const float* __restrict__ w = &CW2[t * MID];
#pragma unroll 4
    for (int m = 0; m < MID; m += 4) {
      const float4 wv = *(const float4*)&w[m];
      const float4 hv = *(const float4*)&h[m];
      acc += hv.x * wv.x;
      acc += hv.y * wv.y;
      acc += hv.z * wv.z;
      acc += hv.w * wv.w;
    }
    h2[t] = sinf(1.5f * acc);
    __syncthreads();
    hlast = h2;
  }

  const float* W2 = (net == 0) ? AW2 : (net == 1) ? BW2 : CW3;
  const float* b2 = (net == 0) ? Ab2 : (net == 1) ? Bb2 : Cb3;

  if (t < KP) {
    float v = 0.0f;
    if (t < RR) {
      float acc = b2[t];
      const float* __restrict__ w = &W2[t * MID];
#pragma unroll 4
      for (int m = 0; m < MID; m += 4) {
        const float4 wv = *(const float4*)&w[m];
        const float4 hv = *(const float4*)&hlast[m];
        acc += hv.x * wv.x;
        acc += hv.y * wv.y;
        acc += hv.z * wv.z;
        acc += hv.w * wv.w;
      }
      v = acc;
    }
    if (net == 0)      Af[i * KP + t] = v;
    else if (net == 1) Bf[i * KP + t] = v;
    else               Cbf[i * KP + t] = f2bf(v);
  }
}

// ---------------- CP contraction via bf16 MFMA ----------------
// R7 contiguous-slab structure (block = (i, j0) -> out[i, j0:j0+64, 0:384],
// bijective XCD swizzle, 48 KB LDS, occ 3, direct staging, 6 barriers)
// with ONE change: waves split K instead of J.
//  * wave w owns all 64 j x k-rows [w*32, w*32+32) of each kt -> each wave
//    reads a DISJOINT 8 KB slice of Ct (was: every wave read all 32 KB).
//    LDS read volume per kt: 144 KB -> 32 KB.
//  * W fragments are kt-invariant (no k dependence) -> all 16 (4 jf x 4 ks)
//    hoisted to registers once (64 VGPR; no other persistent state added).
//  * inner loop per kt: 8 ds_read_b128 + 32 MFMA over 8 independent accs
//    (same ILP and same ks-accumulation order as R7 -> bitwise-identical
//    output) + 8 full-line dwordx4 stores.
__global__ __launch_bounds__(256, 3) void cp_mfma(
    const float* __restrict__ Af, const float* __restrict__ Bf,
    const ushort_t* __restrict__ Cbf, float* __restrict__ out) {
  __shared__ ushort_t Wt[64 * KP];    // 16 KB
  __shared__ ushort_t Ct[128 * KP];   // 32 KB

  // bijective XCD swizzle: 2304 blocks = 8 XCDs x 288
  const int bid = blockIdx.x;
  const int swz = (bid & 7) * 288 + (bid >> 3);
  const int i   = swz / 6;
  const int j0  = (swz % 6) * 64;
  const int t   = threadIdx.x;

  // ---- fold W band [64][128]: 4 threads per j-row, 32 r's each ----
  {
    const int jx = t >> 2;
    const int q  = t & 3;
    const float* __restrict__ arow = Af + (size_t)i * KP + q * 32;
    const float* __restrict__ brow = Bf + (size_t)(j0 + jx) * KP + q * 32;
#pragma unroll
    for (int c = 0; c < 4; ++c) {
      const float4 a0 = *(const float4*)(arow + c * 8);
      const float4 a1 = *(const float4*)(arow + c * 8 + 4);
      const float4 b0 = *(const float4*)(brow + c * 8);
      const float4 b1 = *(const float4*)(brow + c * 8 + 4);
      uint4 wv;
      wv.x = (unsigned)f2bf(a0.x * b0.x) | ((unsigned)f2bf(a0.y * b0.y) << 16);
      wv.y = (unsigned)f2bf(a0.z * b0.z) | ((unsigned)f2bf(a0.w * b0.w) << 16);
      wv.z = (unsigned)f2bf(a1.x * b1.x) | ((unsigned)f2bf(a1.y * b1.y) << 16);
      wv.w = (unsigned)f2bf(a1.z * b1.z) | ((unsigned)f2bf(a1.w * b1.w) << 16);
      *(uint4*)&Wt[SW(jx, q * 4 + c)] = wv;
    }
  }

  const int lane = t & 63;
  const int w    = t >> 6;       // wave owns k-rows [w*32, w*32+32) per kt
  const int m16  = lane & 15;
  const int g    = lane >> 4;

  // per-jf output row bases: j = j0 + jf*16 + m16
  size_t jbase[4];
#pragma unroll
  for (int jf = 0; jf < 4; ++jf)
    jbase[jf] = (size_t)i * NN * NN + (size_t)(j0 + jf * 16 + m16) * NN;

  // ---- staging geometry: thread t handles rows (t>>4)+16*it, chunk t&15
  const int crow = t >> 4;
  const int cch  = t & 15;
  const ushort_t* __restrict__ csrc = Cbf + (size_t)crow * KP + cch * 8;

#define STAGE(KT)                                                            \
  {                                                                          \
    _Pragma("unroll") for (int it = 0; it < 8; ++it) {                       \
      *(uint4*)&Ct[SW(crow + 16 * it, cch)] =                                \
          *(const uint4*)(csrc + (size_t)((KT) * 128 + 16 * it) * KP);       \
    }                                                                        \
  }

#define COMPUTE_STORE(KT)                                                    \
  {                                                                          \
    floatx4 acc[4][2];                                                       \
    _Pragma("unroll") for (int jf = 0; jf < 4; ++jf)                         \
        _Pragma("unroll") for (int kf = 0; kf < 2; ++kf)                     \
            acc[jf][kf] = (floatx4)0.0f;                                     \
    _Pragma("unroll") for (int ks = 0; ks < 4; ++ks) {                       \
      bf16x8 cf[2];                                                          \
      _Pragma("unroll") for (int kf = 0; kf < 2; ++kf)                       \
          cf[kf] = *(const bf16x8*)&Ct[SW(w * 32 + kf * 16 + m16,            \
                                          ks * 4 + g)];                      \
      _Pragma("unroll") for (int jf = 0; jf < 4; ++jf)                       \
          _Pragma("unroll") for (int kf = 0; kf < 2; ++kf)                   \
              acc[jf][kf] = __builtin_amdgcn_mfma_f32_16x16x32_bf16(         \
                  cf[kf], wfr[jf][ks], acc[jf][kf], 0, 0, 0);                \
    }                                                                        \
    const int kb = (KT) * 128 + w * 32 + g * 4;                              \
    _Pragma("unroll") for (int jf = 0; jf < 4; ++jf)                         \
        _Pragma("unroll") for (int kf = 0; kf < 2; ++kf)                     \
            *(floatx4*)&out[jbase[jf] + kb + kf * 16] = acc[jf][kf];         \
  }

  // ---- kt = 0: stage + make Wt/Ct visible, hoist W fragments ----
  STAGE(0);
  __syncthreads();

  bf16x8 wfr[4][4];  // kt-invariant W fragments (4 jf x 4 ks)
#pragma unroll
  for (int jf = 0; jf < 4; ++jf)
#pragma unroll
    for (int ks = 0; ks < 4; ++ks)
      wfr[jf][ks] = *(const bf16x8*)&Wt[SW(jf * 16 + m16, ks * 4 + g)];

  COMPUTE_STORE(0);

  // ---- kt = 1 ----
  __syncthreads();   // all waves done reading Ct(kt0)
  STAGE(1);
  __syncthreads();
  COMPUTE_STORE(1);

  // ---- kt = 2 ----
  __syncthreads();
  STAGE(2);
  __syncthreads();
  COMPUTE_STORE(2);

#undef STAGE
#undef COMPUTE_STORE
}

extern "C" void kernel_launch(void* const* d_in, const int* in_sizes, int n_in,
                              void* d_out, int out_size, void* d_ws, size_t ws_size,
                              hipStream_t stream) {
  const float* A_input = (const float*)d_in[0];
  const float* B_input = (const float*)d_in[1];
  const float* C_input = (const float*)d_in[2];
  const float* A_W1 = (const float*)d_in[3];
  const float* A_b1 = (const float*)d_in[4];
  const float* A_W2 = (const float*)d_in[5];
  const float* A_b2 = (const float*)d_in[6];
  const float* B_W1 = (const float*)d_in[7];
  const float* B_b1 = (const float*)d_in[8];
  const float* B_W2 = (const float*)d_in[9];
  const float* B_b2 = (const float*)d_in[10];
  const float* C_W1 = (const float*)d_in[11];
  const float* C_b1 = (const float*)d_in[12];
  const float* C_W2 = (const float*)d_in[13];
  const float* C_b2 = (const float*)d_in[14];
  const float* C_W3 = (const float*)d_in[15];
  const float* C_b3 = (const float*)d_in[16];

  // ws layout: Af fp32 [384][128] | Bf fp32 [384][128] | Cbf bf16 [384][128]
  float* Af = (float*)d_ws;                       // 196,608 B
  float* Bf = Af + NN * KP;                       // 196,608 B
  ushort_t* Cbf = (ushort_t*)(Bf + NN * KP);      //  98,304 B  (total 480 KB)

  dim3 fgrid(NN, 3);
  factors_kernel<<<fgrid, 256, 0, stream>>>(
      A_input, B_input, C_input,
      A_W1, A_b1, A_W2, A_b2,
      B_W1, B_b1, B_W2, B_b2,
      C_W1, C_b1, C_W2, C_b2, C_W3, C_b3,
      Af, Bf, Cbf);

  // 2304 blocks = (NN/64 j-slabs) x (NN i)
  cp_mfma<<<dim3((NN / 64) * NN), 256, 0, stream>>>(Af, Bf, Cbf, (float*)d_out);
}

// Round 10
// 290.525 us; speedup vs baseline: 1.1895x; 1.0014x over previous
//
#include <hip/hip_runtime.h>
#include <hip/hip_bf16.h>

#define RR 100
#define MID 256
#define NN 384
#define KP 128   // rank padded to 128 (zeros in r=100..127)

typedef __attribute__((ext_vector_type(8))) __bf16 bf16x8;
typedef __attribute__((ext_vector_type(4))) float floatx4;
typedef unsigned short ushort_t;

// Swizzled LDS offset (elements) for row-major [rows][KP] bf16 tiles stored as
// 16 chunks of 8 bf16 per row; chunk index XOR'd with (row&15) so that
// MFMA fragment reads (16 rows x same chunk) spread across all 32 banks.
#define SW(row, ch) ((((row) << 7)) + ((((ch) ^ ((row) & 15))) << 3))

__device__ __forceinline__ ushort_t f2bf(float f) {
  __hip_bfloat16 h = __float2bfloat16(f);
  return __builtin_bit_cast(ushort_t, h);
}

// ---------------- Factor nets (all three in one launch) ----------------
__global__ __launch_bounds__(256) void factors_kernel(
    const float* __restrict__ xA, const float* __restrict__ xB,
    const float* __restrict__ xC,
    const float* __restrict__ AW1, const float* __restrict__ Ab1,
    const float* __restrict__ AW2, const float* __restrict__ Ab2,
    const float* __restrict__ BW1, const float* __restrict__ Bb1,
    const float* __restrict__ BW2, const float* __restrict__ Bb2,
    const float* __restrict__ CW1, const float* __restrict__ Cb1,
    const float* __restrict__ CW2, const float* __restrict__ Cb2,
    const float* __restrict__ CW3, const float* __restrict__ Cb3,
    float* __restrict__ Af, float* __restrict__ Bf,
    ushort_t* __restrict__ Cbf) {
  __shared__ float h[MID];
  __shared__ float h2[MID];
  const int i = blockIdx.x;
  const int net = blockIdx.y;
  const int t = threadIdx.x;

  const float* x  = (net == 0) ? xA  : (net == 1) ? xB  : xC;
  const float* W1 = (net == 0) ? AW1 : (net == 1) ? BW1 : CW1;
  const float* b1 = (net == 0) ? Ab1 : (net == 1) ? Bb1 : Cb1;

  const float xv = x[i];
  h[t] = sinf(1.5f * (xv * W1[t] + b1[t]));
  __syncthreads();

  const float* hlast = h;
  if (net == 2) {  // block-uniform branch
    float acc = Cb2[t];
    const float* __restrict__ w = &CW2[t * MID];
#pragma unroll 4
    for (int m = 0; m < MID; m += 4) {
      const float4 wv = *(const float4*)&w[m];
      const float4 hv = *(const float4*)&h[m];
      acc += hv.x * wv.x;
      acc += hv.y * wv.y;
      acc += hv.z * wv.z;
      acc += hv.w * wv.w;
    }
    h2[t] = sinf(1.5f * acc);
    __syncthreads();
    hlast = h2;
  }

  const float* W2 = (net == 0) ? AW2 : (net == 1) ? BW2 : CW3;
  const float* b2 = (net == 0) ? Ab2 : (net == 1) ? Bb2 : Cb3;

  if (t < KP) {
    float v = 0.0f;
    if (t < RR) {
      float acc = b2[t];
      const float* __restrict__ w = &W2[t * MID];
#pragma unroll 4
      for (int m = 0; m < MID; m += 4) {
        const float4 wv = *(const float4*)&w[m];
        const float4 hv = *(const float4*)&hlast[m];
        acc += hv.x * wv.x;
        acc += hv.y * wv.y;
        acc += hv.z * wv.z;
        acc += hv.w * wv.w;
      }
      v = acc;
    }
    if (net == 0)      Af[i * KP + t] = v;
    else if (net == 1) Bf[i * KP + t] = v;
    else               Cbf[i * KP + t] = f2bf(v);
  }
}

// ---------------- CP contraction via bf16 MFMA ----------------
// R9 structure (contiguous slab per block, XCD swizzle, k-split waves,
// wfr hoisted, occ 3) with ONE change: the epilogue goes through LDS.
// acc -> Ot (32 KB, aliasing Ct which is dead between the post-compute
// barrier and the next stage) with chunk^row&7 swizzle (conflict-free),
// then a cooperative read-back issues stores where each wave instruction
// writes two contiguous 512 B runs (32 lanes x 16 B per j-row) instead of
// sixteen scattered 64 B fragments. Theory: HBM write efficiency is set by
// store-instruction-order spatial linearity (L2 does not reassemble: 9 MB
// of interleaved dirty tiles per 4 MB XCD-L2 evict in LRU order, and R5's
// NT probe showed the raw instr-order pattern costs only ~10 us more than
// through-L2 -> neither path sees linear runs today).
__global__ __launch_bounds__(256, 3) void cp_mfma(
    const float* __restrict__ Af, const float* __restrict__ Bf,
    const ushort_t* __restrict__ Cbf, float* __restrict__ out) {
  __shared__ __align__(16) ushort_t Wt[64 * KP];    // 16 KB
  __shared__ __align__(16) ushort_t Ct[128 * KP];   // 32 KB (aliased as Ot)
  float* Ot = reinterpret_cast<float*>(Ct);         // [64 j][128 k] f32

  // bijective XCD swizzle: 2304 blocks = 8 XCDs x 288
  const int bid = blockIdx.x;
  const int swz = (bid & 7) * 288 + (bid >> 3);
  const int i   = swz / 6;
  const int j0  = (swz % 6) * 64;
  const int t   = threadIdx.x;

  // ---- fold W band [64][128]: 4 threads per j-row, 32 r's each ----
  {
    const int jx = t >> 2;
    const int q  = t & 3;
    const float* __restrict__ arow = Af + (size_t)i * KP + q * 32;
    const float* __restrict__ brow = Bf + (size_t)(j0 + jx) * KP + q * 32;
#pragma unroll
    for (int c = 0; c < 4; ++c) {
      const float4 a0 = *(const float4*)(arow + c * 8);
      const float4 a1 = *(const float4*)(arow + c * 8 + 4);
      const float4 b0 = *(const float4*)(brow + c * 8);
      const float4 b1 = *(const float4*)(brow + c * 8 + 4);
      uint4 wv;
      wv.x = (unsigned)f2bf(a0.x * b0.x) | ((unsigned)f2bf(a0.y * b0.y) << 16);
      wv.y = (unsigned)f2bf(a0.z * b0.z) | ((unsigned)f2bf(a0.w * b0.w) << 16);
      wv.z = (unsigned)f2bf(a1.x * b1.x) | ((unsigned)f2bf(a1.y * b1.y) << 16);
      wv.w = (unsigned)f2bf(a1.z * b1.z) | ((unsigned)f2bf(a1.w * b1.w) << 16);
      *(uint4*)&Wt[SW(jx, q * 4 + c)] = wv;
    }
  }

  const int lane = t & 63;
  const int w    = t >> 6;       // wave owns k-rows [w*32, w*32+32) per kt
  const int m16  = lane & 15;
  const int g    = lane >> 4;

  // ---- staging geometry: thread t handles rows (t>>4)+16*it, chunk t&15
  const int crow = t >> 4;
  const int cch  = t & 15;
  const ushort_t* __restrict__ csrc = Cbf + (size_t)crow * KP + cch * 8;

  // ---- copy-out geometry: rows (t>>5)+8*it, 16B chunk t&31 of 32/row ----
  const int orow = t >> 5;
  const int och  = t & 31;
  const size_t obase0 = (size_t)i * NN * NN + (size_t)j0 * NN;

#define STAGE(KT)                                                            \
  {                                                                          \
    _Pragma("unroll") for (int it = 0; it < 8; ++it) {                       \
      *(uint4*)&Ct[SW(crow + 16 * it, cch)] =                                \
          *(const uint4*)(csrc + (size_t)((KT) * 128 + 16 * it) * KP);       \
    }                                                                        \
  }

  // ---- kt = 0: stage + make Wt/Ct visible, hoist W fragments ----
  STAGE(0);
  __syncthreads();

  bf16x8 wfr[4][4];  // kt-invariant W fragments (4 jf x 4 ks)
#pragma unroll
  for (int jf = 0; jf < 4; ++jf)
#pragma unroll
    for (int ks = 0; ks < 4; ++ks)
      wfr[jf][ks] = *(const bf16x8*)&Wt[SW(jf * 16 + m16, ks * 4 + g)];

#pragma unroll 1
  for (int kt = 0; kt < 3; ++kt) {
    // ---- COMPUTE: 8 ds_read + 32 MFMA over 8 independent accs ----
    floatx4 acc[4][2];
#pragma unroll
    for (int jf = 0; jf < 4; ++jf)
#pragma unroll
      for (int kf = 0; kf < 2; ++kf) acc[jf][kf] = (floatx4)0.0f;

#pragma unroll
    for (int ks = 0; ks < 4; ++ks) {
      bf16x8 cf[2];
#pragma unroll
      for (int kf = 0; kf < 2; ++kf)
        cf[kf] = *(const bf16x8*)&Ct[SW(w * 32 + kf * 16 + m16, ks * 4 + g)];
#pragma unroll
      for (int jf = 0; jf < 4; ++jf)
#pragma unroll
        for (int kf = 0; kf < 2; ++kf)
          acc[jf][kf] = __builtin_amdgcn_mfma_f32_16x16x32_bf16(
              cf[kf], wfr[jf][ks], acc[jf][kf], 0, 0, 0);
    }
    __syncthreads();  // all waves done reading Ct(kt); Ct space reusable

    // ---- ACC -> Ot (swizzled, conflict-free) ----
#pragma unroll
    for (int jf = 0; jf < 4; ++jf) {
      const int row = jf * 16 + m16;
#pragma unroll
      for (int kf = 0; kf < 2; ++kf) {
        const int ch = (w * 8 + kf * 4 + g) ^ (row & 7);
        *(floatx4*)&Ot[row * 128 + ch * 4] = acc[jf][kf];
      }
    }
    __syncthreads();  // Ot complete

    // ---- COPYREAD: 8 ds_read_b128 in fill-order ----
    floatx4 o[8];
#pragma unroll
    for (int it = 0; it < 8; ++it) {
      const int r = orow + 8 * it;
      const int c = och ^ (r & 7);
      o[it] = *(const floatx4*)&Ot[r * 128 + c * 4];
    }
    __syncthreads();  // all reads done; Ct space free for next stage

    // ---- next-tile stage (LDS writes) + linear stores (regs only) ----
    if (kt == 0) { STAGE(1); }
    else if (kt == 1) { STAGE(2); }
#pragma unroll
    for (int it = 0; it < 8; ++it) {
      const int r = orow + 8 * it;
      *(floatx4*)&out[obase0 + (size_t)r * NN + kt * 128 + och * 4] = o[it];
    }
    if (kt < 2) __syncthreads();  // Ct(kt+1) visible
  }
}

extern "C" void kernel_launch(void* const* d_in, const int* in_sizes, int n_in,
                              void* d_out, int out_size, void* d_ws, size_t ws_size,
                              hipStream_t stream) {
  const float* A_input = (const float*)d_in[0];
  const float* B_input = (const float*)d_in[1];
  const float* C_input = (const float*)d_in[2];
  const float* A_W1 = (const float*)d_in[3];
  const float* A_b1 = (const float*)d_in[4];
  const float* A_W2 = (const float*)d_in[5];
  const float* A_b2 = (const float*)d_in[6];
  const float* B_W1 = (const float*)d_in[7];
  const float* B_b1 = (const float*)d_in[8];
  const float* B_W2 = (const float*)d_in[9];
  const float* B_b2 = (const float*)d_in[10];
  const float* C_W1 = (const float*)d_in[11];
  const float* C_b1 = (const float*)d_in[12];
  const float* C_W2 = (const float*)d_in[13];
  const float* C_b2 = (const float*)d_in[14];
  const float* C_W3 = (const float*)d_in[15];
  const float* C_b3 = (const float*)d_in[16];

  // ws layout: Af fp32 [384][128] | Bf fp32 [384][128] | Cbf bf16 [384][128]
  float* Af = (float*)d_ws;                       // 196,608 B
  float* Bf = Af + NN * KP;                       // 196,608 B
  ushort_t* Cbf = (ushort_t*)(Bf + NN * KP);      //  98,304 B  (total 480 KB)

  dim3 fgrid(NN, 3);
  factors_kernel<<<fgrid, 256, 0, stream>>>(
      A_input, B_input, C_input,
      A_W1, A_b1, A_W2, A_b2,
      B_W1, B_b1, B_W2, B_b2,
      C_W1, C_b1, C_W2, C_b2, C_W3, C_b3,
      Af, Bf, Cbf);

  // 2304 blocks = (NN/64 j-slabs) x (NN i)
  cp_mfma<<<dim3((NN / 64) * NN), 256, 0, stream>>>(Af, Bf, Cbf, (float*)d_out);
}